// Round 1
// 323.022 us; speedup vs baseline: 1.1169x; 1.1169x over previous
//
#include <hip/hip_runtime.h>
#include <hip/hip_bf16.h>
#include <math.h>
#include <float.h>

#ifndef M_PI
#define M_PI 3.14159265358979323846
#endif

// Problem constants
#define NBANDS 160      // B*NB = 32*5
#define RR 96           // rows per band
#define TT 2048         // time samples
#define NTRIL 4560      // 96*95/2
#define A_ELEMS ((size_t)NBANDS * RR * RR)
#define NBIN 16384
#define MAXCAND 512

// XOR bank swizzle for the FFT kernel
#define PHI(L) ((L) ^ (((L) >> 5) & 31))

typedef float  f32x4  __attribute__((ext_vector_type(4)));
typedef __bf16 bf16x8 __attribute__((ext_vector_type(8)));
typedef __bf16 bf16x4 __attribute__((ext_vector_type(4)));

// ---------- block reductions (256 threads = 4 waves) ----------
__device__ inline double blockReduceSum(double v, double* sred) {
    for (int off = 32; off > 0; off >>= 1) v += __shfl_down(v, off, 64);
    int lane = threadIdx.x & 63, wid = threadIdx.x >> 6;
    if (lane == 0) sred[wid] = v;
    __syncthreads();
    int nw = (blockDim.x + 63) >> 6;
    if (threadIdx.x == 0) {
        double r = sred[0];
        for (int i = 1; i < nw; i++) r += sred[i];
        sred[0] = r;
    }
    __syncthreads();
    double r = sred[0];
    __syncthreads();
    return r;
}

// batched reductions: 4 (or 2) independent shuffle chains pipelined, one
// barrier set instead of per-value. blockDim MUST be 256 (4 waves).
__device__ inline void blockReduceSum4(double v0, double v1, double v2, double v3,
                                       double* sred, double out[4]) {
    for (int off = 32; off > 0; off >>= 1) {
        v0 += __shfl_down(v0, off, 64);
        v1 += __shfl_down(v1, off, 64);
        v2 += __shfl_down(v2, off, 64);
        v3 += __shfl_down(v3, off, 64);
    }
    int lane = threadIdx.x & 63, wid = threadIdx.x >> 6;
    if (lane == 0) {
        sred[wid * 4 + 0] = v0; sred[wid * 4 + 1] = v1;
        sred[wid * 4 + 2] = v2; sred[wid * 4 + 3] = v3;
    }
    __syncthreads();
    if (threadIdx.x < 4) {
        double r = sred[threadIdx.x] + sred[4 + threadIdx.x]
                 + sred[8 + threadIdx.x] + sred[12 + threadIdx.x];
        sred[16 + threadIdx.x] = r;
    }
    __syncthreads();
    out[0] = sred[16]; out[1] = sred[17]; out[2] = sred[18]; out[3] = sred[19];
    __syncthreads();
}

__device__ inline void blockReduceSum2(double v0, double v1,
                                       double* sred, double out[2]) {
    for (int off = 32; off > 0; off >>= 1) {
        v0 += __shfl_down(v0, off, 64);
        v1 += __shfl_down(v1, off, 64);
    }
    int lane = threadIdx.x & 63, wid = threadIdx.x >> 6;
    if (lane == 0) { sred[wid * 2 + 0] = v0; sred[wid * 2 + 1] = v1; }
    __syncthreads();
    if (threadIdx.x < 2) {
        double r = sred[threadIdx.x] + sred[2 + threadIdx.x]
                 + sred[4 + threadIdx.x] + sred[6 + threadIdx.x];
        sred[8 + threadIdx.x] = r;
    }
    __syncthreads();
    out[0] = sred[8]; out[1] = sred[9];
    __syncthreads();
}

__device__ inline void blockReduceMax2(double v0, double v1,
                                       double* sred, double out[2]) {
    for (int off = 32; off > 0; off >>= 1) {
        v0 = fmax(v0, __shfl_down(v0, off, 64));
        v1 = fmax(v1, __shfl_down(v1, off, 64));
    }
    int lane = threadIdx.x & 63, wid = threadIdx.x >> 6;
    if (lane == 0) { sred[wid * 2 + 0] = v0; sred[wid * 2 + 1] = v1; }
    __syncthreads();
    if (threadIdx.x < 2) {
        double r = fmax(fmax(sred[threadIdx.x], sred[2 + threadIdx.x]),
                        fmax(sred[4 + threadIdx.x], sred[6 + threadIdx.x]));
        sred[8 + threadIdx.x] = r;
    }
    __syncthreads();
    out[0] = sred[8]; out[1] = sred[9];
    __syncthreads();
}

// ---------- K0: twiddle table  tw[k] = exp(-2*pi*i*k/2048), k<1024 (fp32) ----------
__global__ void twiddle_kernel(float* tw) {
    int k = blockIdx.x * blockDim.x + threadIdx.x;
    if (k < 1024) {
        double ang = -2.0 * M_PI * (double)k / 2048.0;
        tw[2 * k]     = (float)cos(ang);
        tw[2 * k + 1] = (float)sin(ang);
    }
}

// DIT butterfly on register pair (r1, r2) with twiddle (WR, WI)
#define BFLY(r1, r2, WR, WI) do { \
    float _wr = (WR), _wi = (WI); \
    float _tr = _wr * yr[r2] - _wi * yi[r2]; \
    float _ti = _wr * yi[r2] + _wi * yr[r2]; \
    yr[r2] = yr[r1] - _tr; yi[r2] = yi[r1] - _ti; \
    yr[r1] += _tr; yi[r1] += _ti; } while (0)

// ---------- K1: per-row stats + fp32 register radix-8 FFT entropy ----------
// f32 per-thread accumulation (8 terms each -> negligible rounding), f64 only
// in the 256->1 tree; __logf for the entropy (feature-level accuracy ~1e-6);
// batched reductions to cut dependent-shuffle latency + barrier count.
__global__ __launch_bounds__(256) void rowstat_fft_kernel(
    const float* __restrict__ wc, const float* __restrict__ tw,
    double* __restrict__ rowstats)
{
    __shared__ float re[TT];
    __shared__ float im[TT];
    __shared__ double sred[24];
    __shared__ float bcast[4];

    int t = threadIdx.x;
    int g0 = blockIdx.x * 2;
    int g1 = g0 + 1;

    int band = g0 / RR, r0 = g0 % RR;
    int b = band / 5, nb = band % 5;
    size_t base0 = ((size_t)(b * RR + r0) * 5 + nb) * TT;
    size_t base1 = base0 + (size_t)5 * TT;

    float s0 = 0.f, s1 = 0.f, q0 = 0.f, q1 = 0.f, m0 = 0.f, m1 = 0.f;
#pragma unroll
    for (int c = 0; c < 8; c++) {
        int i = t + c * 256;
        float af = wc[base0 + i];
        float bf = wc[base1 + i];
        int P = PHI(i);
        re[P] = af; im[P] = bf;
        s0 += af; s1 += bf;
        q0 = fmaf(af, af, q0); q1 = fmaf(bf, bf, q1);
        m0 = fmaxf(m0, fabsf(af)); m1 = fmaxf(m1, fabsf(bf));
    }
    __syncthreads();

    double S4[4], M2[2];
    blockReduceSum4((double)s0, (double)s1, (double)q0, (double)q1, sred, S4);
    blockReduceMax2((double)m0, (double)m1, sred, M2);
    double SUM0 = S4[0], SUM1 = S4[1], SQ0 = S4[2], SQ1 = S4[3];
    double MX0 = M2[0], MX1 = M2[1];

    float yr[8], yi[8];

#pragma unroll
    for (int j = 0; j < 8; j++) {
        int p = 8 * t + j;
        int L = (int)(__brev((unsigned)p) >> 21);
        int P = PHI(L);
        yr[j] = re[P]; yi[j] = im[P];
    }

    const float RC = 0.70710678f;
    BFLY(0, 1, 1.0f, 0.0f); BFLY(2, 3, 1.0f, 0.0f);
    BFLY(4, 5, 1.0f, 0.0f); BFLY(6, 7, 1.0f, 0.0f);
    BFLY(0, 2, 1.0f, 0.0f); BFLY(1, 3, 0.0f, -1.0f);
    BFLY(4, 6, 1.0f, 0.0f); BFLY(5, 7, 0.0f, -1.0f);
    BFLY(0, 4, 1.0f, 0.0f); BFLY(1, 5, RC, -RC);
    BFLY(2, 6, 0.0f, -1.0f); BFLY(3, 7, -RC, -RC);

    __syncthreads();
#pragma unroll
    for (int j = 0; j < 8; j++) {
        int P = PHI(8 * t + j);
        re[P] = yr[j]; im[P] = yi[j];
    }
    __syncthreads();
    int oo = t & 7;
    int bb64 = 4 * ((t >> 3) & 7) + (t >> 6);
#pragma unroll
    for (int k = 0; k < 8; k++) {
        int P = PHI(64 * bb64 + 8 * k + oo);
        yr[k] = re[P]; yi[k] = im[P];
    }

    {
        int k0 = oo << 7;
        float w0r = tw[2 * k0], w0i = tw[2 * k0 + 1];
        BFLY(0, 1, w0r, w0i); BFLY(2, 3, w0r, w0i);
        BFLY(4, 5, w0r, w0i); BFLY(6, 7, w0r, w0i);
        int ka = oo << 6, kb = (oo + 8) << 6;
        float war = tw[2 * ka], wai = tw[2 * ka + 1];
        float wbr = tw[2 * kb], wbi = tw[2 * kb + 1];
        BFLY(0, 2, war, wai); BFLY(1, 3, wbr, wbi);
        BFLY(4, 6, war, wai); BFLY(5, 7, wbr, wbi);
        int kc0 = oo << 5, kc1 = (oo + 8) << 5, kc2 = (oo + 16) << 5, kc3 = (oo + 24) << 5;
        BFLY(0, 4, tw[2 * kc0], tw[2 * kc0 + 1]);
        BFLY(1, 5, tw[2 * kc1], tw[2 * kc1 + 1]);
        BFLY(2, 6, tw[2 * kc2], tw[2 * kc2 + 1]);
        BFLY(3, 7, tw[2 * kc3], tw[2 * kc3 + 1]);
    }

    __syncthreads();
#pragma unroll
    for (int k = 0; k < 8; k++) {
        int P = PHI(64 * bb64 + 8 * k + oo);
        re[P] = yr[k]; im[P] = yi[k];
    }
    __syncthreads();
    int O3 = t & 63, Wq = t >> 6;
#pragma unroll
    for (int s = 0; s < 2; s++) {
        int B3 = Wq + 4 * s;
#pragma unroll
        for (int k = 0; k < 4; k++) {
            int P = PHI(256 * B3 + 64 * k + O3);
            yr[4 * s + k] = re[P]; yi[4 * s + k] = im[P];
        }
    }

    {
        int kt = O3 << 4;
        float w0r = tw[2 * kt], w0i = tw[2 * kt + 1];
        int ka = O3 << 3, kb = (O3 + 64) << 3;
        float war = tw[2 * ka], wai = tw[2 * ka + 1];
        float wbr = tw[2 * kb], wbi = tw[2 * kb + 1];
        BFLY(0, 1, w0r, w0i); BFLY(2, 3, w0r, w0i);
        BFLY(4, 5, w0r, w0i); BFLY(6, 7, w0r, w0i);
        BFLY(0, 2, war, wai); BFLY(1, 3, wbr, wbi);
        BFLY(4, 6, war, wai); BFLY(5, 7, wbr, wbi);
    }

    __syncthreads();
#pragma unroll
    for (int s = 0; s < 2; s++) {
        int B3 = Wq + 4 * s;
#pragma unroll
        for (int k = 0; k < 4; k++) {
            int P = PHI(256 * B3 + 64 * k + O3);
            re[P] = yr[4 * s + k]; im[P] = yi[4 * s + k];
        }
    }
    __syncthreads();
#pragma unroll
    for (int k = 0; k < 8; k++) {
        int P = PHI(256 * k + t);
        yr[k] = re[P]; yi[k] = im[P];
    }

    {
        int k9 = t << 2;
        float w0r = tw[2 * k9], w0i = tw[2 * k9 + 1];
        BFLY(0, 1, w0r, w0i); BFLY(2, 3, w0r, w0i);
        BFLY(4, 5, w0r, w0i); BFLY(6, 7, w0r, w0i);
        int ka = t << 1, kb = (t + 256) << 1;
        float war = tw[2 * ka], wai = tw[2 * ka + 1];
        float wbr = tw[2 * kb], wbi = tw[2 * kb + 1];
        BFLY(0, 2, war, wai); BFLY(1, 3, wbr, wbi);
        BFLY(4, 6, war, wai); BFLY(5, 7, wbr, wbi);
        BFLY(0, 4, tw[2 * t], tw[2 * t + 1]);
        BFLY(1, 5, tw[2 * (t + 256)], tw[2 * (t + 256) + 1]);
        BFLY(2, 6, tw[2 * (t + 512)], tw[2 * (t + 512) + 1]);
        BFLY(3, 7, tw[2 * (t + 768)], tw[2 * (t + 768) + 1]);
    }

    __syncthreads();
#pragma unroll
    for (int k = 0; k < 8; k++) {
        int P = PHI(256 * k + t);
        re[P] = yr[k]; im[P] = yi[k];
    }
    __syncthreads();

    float psa[8], psb[8];
#pragma unroll
    for (int k = 0; k < 8; k++) {
        int q = (2048 - t - 256 * k) & 2047;
        int P = PHI(q);
        float prr = re[P], pii = im[P];
        float sr = yr[k] + prr, di = yi[k] - pii;
        float si = yi[k] + pii, dr = yr[k] - prr;
        psa[k] = 0.25f * (sr * sr + di * di);
        psb[k] = 0.25f * (si * si + dr * dr);
    }

    float la = 0.f, lb = 0.f;
#pragma unroll
    for (int k = 0; k < 8; k++) { la += psa[k]; lb += psb[k]; }
    double SS[2];
    blockReduceSum2((double)la, (double)lb, sred, SS);
    double SAall = SS[0], SBall = SS[1];
    if (t == 0) {
        bcast[0] = psa[0]; bcast[1] = psa[4];
        bcast[2] = psb[0]; bcast[3] = psb[4];
    }
    __syncthreads();
    double Sa = 0.5 * (SAall + (double)bcast[0] - (double)bcast[1]);
    double Sb = 0.5 * (SBall + (double)bcast[2] - (double)bcast[3]);
    if (Sa == 0.0) Sa = 1.0;
    if (Sb == 0.0) Sb = 1.0;
    float invSa = (float)(1.0 / Sa), invSb = (float)(1.0 / Sb);

    float ea = 0.f, eb = 0.f;
#pragma unroll
    for (int k = 0; k < 8; k++) {
        float pa = psa[k] * invSa;
        float pb = psb[k] * invSb;
        ea += pa * __logf(pa + 1e-10f);
        eb += pb * __logf(pb + 1e-10f);
    }
    double EE[2];
    blockReduceSum2((double)ea, (double)eb, sred, EE);
    double EAall = EE[0], EBall = EE[1];

    if (t == 0) {
        float pa0 = psa[0] * invSa, pa4 = psa[4] * invSa;
        float pb0 = psb[0] * invSb, pb4 = psb[4] * invSb;
        double TA = 0.5 * (EAall + (double)(pa0 * __logf(pa0 + 1e-10f))
                                 - (double)(pa4 * __logf(pa4 + 1e-10f)));
        double TB = 0.5 * (EBall + (double)(pb0 * __logf(pb0 + 1e-10f))
                                 - (double)(pb4 * __logf(pb4 + 1e-10f)));
        double mean0 = SUM0 / (double)TT;
        double mean1 = SUM1 / (double)TT;
        double nsq0 = SQ0 - (double)TT * mean0 * mean0; if (nsq0 < 0) nsq0 = 0;
        double nsq1 = SQ1 - (double)TT * mean1 * mean1; if (nsq1 < 0) nsq1 = 0;
        double* w0 = rowstats + (size_t)g0 * 6;
        double* w1 = rowstats + (size_t)g1 * 6;
        double n0 = sqrt(nsq0), n1 = sqrt(nsq1);
        w0[0] = mean0; w0[1] = (n0 == 0.0 ? 1.0 : n0); w0[2] = sqrt(nsq0 / 2047.0);
        w0[3] = SQ0;   w0[4] = MX0;                    w0[5] = -TA;
        w1[0] = mean1; w1[1] = (n1 == 0.0 ? 1.0 : n1); w1[2] = sqrt(nsq1 / 2047.0);
        w1[3] = SQ1;   w1[4] = MX1;                    w1[5] = -TB;
    }
}

// ---------- K2a: zero the Gram staging region (fallback path only) ----------
__global__ void zero_kernel(float4* __restrict__ p, int n4) {
    int i = blockIdx.x * blockDim.x + threadIdx.x;
    if (i < n4) p[i] = make_float4(0.f, 0.f, 0.f, 0.f);
}

// ---------- K2b: MFMA Gram (hi/lo bf16 split, fp32 MFMA accum) ----------
// grid = NBANDS * KS; block = 384 thr = 6 waves; wave w computes rows
// [16w,16w+16) x all 96 cols for its K-chunk of 256.
// USE_PART=true: each chunk-block stores its full 96x96 partial tile to
// workspace (no atomics); normalize folds the 8-way sum. USE_PART=false:
// legacy atomicAdd K-reduce into G (used when ws is too small).
#define KS 8
#define CHUNK 256
#define BKS 64
#define GPITCH 72
template <bool USE_PART>
__global__ __launch_bounds__(384) void gram_mfma_kernel(
    const float* __restrict__ wc, float* __restrict__ G)
{
    __shared__ __attribute__((aligned(16))) __bf16 sh_hi[RR][GPITCH];
    __shared__ __attribute__((aligned(16))) __bf16 sh_lo[RR][GPITCH];

    int bid = blockIdx.x;
    int band = bid / KS, chunk = bid % KS;
    int b = band / 5, nb = band % 5;
    size_t bandbase = ((size_t)b * RR * 5 + nb) * TT + (size_t)chunk * CHUNK;

    int t = threadIdx.x;
    int wave = t >> 6, lane = t & 63;
    int m16 = lane & 15, quad = lane >> 4;
    int arow = wave * 16 + m16;

    f32x4 acc[6];
#pragma unroll
    for (int ct = 0; ct < 6; ct++) acc[ct] = (f32x4){0.f, 0.f, 0.f, 0.f};

    for (int stage = 0; stage < CHUNK / BKS; stage++) {
        int k0 = stage * BKS;
        // stage-load 96 x 64 fp32 -> hi/lo bf16 in LDS
#pragma unroll
        for (int i = 0; i < 4; i++) {
            int gid = t + i * 384;          // 0..1535
            int row = gid >> 4, c4 = gid & 15;
            float4 v = *(const float4*)(wc + bandbase + (size_t)row * (5 * TT) + k0 + c4 * 4);
            __bf16 h0 = (__bf16)v.x, h1 = (__bf16)v.y, h2 = (__bf16)v.z, h3 = (__bf16)v.w;
            __bf16 l0 = (__bf16)(v.x - (float)h0);
            __bf16 l1 = (__bf16)(v.y - (float)h1);
            __bf16 l2 = (__bf16)(v.z - (float)h2);
            __bf16 l3 = (__bf16)(v.w - (float)h3);
            *(bf16x4*)&sh_hi[row][c4 * 4] = (bf16x4){h0, h1, h2, h3};
            *(bf16x4*)&sh_lo[row][c4 * 4] = (bf16x4){l0, l1, l2, l3};
        }
        __syncthreads();
#pragma unroll
        for (int ks = 0; ks < BKS / 32; ks++) {
            int ko = ks * 32 + quad * 8;
            bf16x8 ah = *(const bf16x8*)&sh_hi[arow][ko];
            bf16x8 al = *(const bf16x8*)&sh_lo[arow][ko];
#pragma unroll
            for (int ct = 0; ct < 6; ct++) {
                int brow = ct * 16 + m16;
                bf16x8 bh = *(const bf16x8*)&sh_hi[brow][ko];
                bf16x8 bl = *(const bf16x8*)&sh_lo[brow][ko];
                acc[ct] = __builtin_amdgcn_mfma_f32_16x16x32_bf16(ah, bh, acc[ct], 0, 0, 0);
                acc[ct] = __builtin_amdgcn_mfma_f32_16x16x32_bf16(ah, bl, acc[ct], 0, 0, 0);
                acc[ct] = __builtin_amdgcn_mfma_f32_16x16x32_bf16(al, bh, acc[ct], 0, 0, 0);
            }
        }
        __syncthreads();
    }

    if (USE_PART) {
        float* Gp = G + (size_t)bid * (RR * RR);   // per-chunk partial tile
#pragma unroll
        for (int ct = 0; ct < 6; ct++) {
#pragma unroll
            for (int r = 0; r < 4; r++) {
                int grow = wave * 16 + quad * 4 + r;
                int gcol = ct * 16 + m16;
                Gp[grow * RR + gcol] = acc[ct][r];
            }
        }
    } else {
        float* Gb = G + (size_t)band * (RR * RR);
#pragma unroll
        for (int ct = 0; ct < 6; ct++) {
#pragma unroll
            for (int r = 0; r < 4; r++) {
                int grow = wave * 16 + quad * 4 + r;
                int gcol = ct * 16 + m16;
                atomicAdd(&Gb[grow * RR + gcol], acc[ct][r]);
            }
        }
    }
}

// ---------- K2c: (sum partials) + normalize Gram -> correlation C ----------
template <bool USE_PART>
__global__ __launch_bounds__(256) void normalize_kernel(
    float* __restrict__ G, const float* __restrict__ Gpart,
    const double* __restrict__ rowstats)
{
    int e = blockIdx.x * 256 + threadIdx.x;
    if (e >= (int)(NBANDS * RR * RR)) return;
    int band = e / (RR * RR);
    int rem = e % (RR * RR);
    int i = rem / RR, j = rem % RR;
    double g;
    if (USE_PART) {
        const float* p = Gpart + (size_t)band * KS * (RR * RR) + rem;
        float acc = 0.f;
#pragma unroll
        for (int c = 0; c < KS; c++) acc += p[(size_t)c * (RR * RR)];
        g = (double)acc;
    } else {
        g = (double)G[e];
    }
    const double* rsi = rowstats + (size_t)(band * RR + i) * 6;
    const double* rsj = rowstats + (size_t)(band * RR + j) * 6;
    double c = (g - (double)TT * rsi[0] * rsj[0]) / (rsi[1] * rsj[1]);
    if (i == j) c = 0.0;
    G[e] = (float)c;
}

// ---------- K3: per-band 0.8-quantile of |C[tril]| via LDS histogram select ----------
__global__ __launch_bounds__(256) void quantile_kernel(
    const float* __restrict__ C, double* __restrict__ thr)
{
    __shared__ int hist[NBIN];
    __shared__ int chunk[256];
    __shared__ float cand[MAXCAND];
    __shared__ int ctrl[4];

    int band = blockIdx.x, t = threadIdx.x;
    const float* Cb = C + (size_t)band * (RR * RR);

    for (int i = t; i < NBIN; i += 256) hist[i] = 0;
    if (t == 0) ctrl[3] = 0;
    __syncthreads();

    for (int idx = t; idx < RR * RR; idx += 256) {
        int i = idx / RR, j = idx % RR;
        if (j < i) {
            float val = fabsf(Cb[idx]);
            int bin = (int)(val * (float)NBIN);
            bin = bin > (NBIN - 1) ? (NBIN - 1) : bin;
            atomicAdd(&hist[bin], 1);
        }
    }
    __syncthreads();

    int cs = 0;
    for (int i = 0; i < 64; i++) cs += hist[t * 64 + i];
    chunk[t] = cs;
    __syncthreads();

    if (t == 0) {
        int r0 = 3647, r1 = 3648;
        int cum = 0, c0 = 0;
        while (c0 < 256 && cum + chunk[c0] <= r0) { cum += chunk[c0]; c0++; }
        int bin = c0 * 64, cb = cum;
        while (cb + hist[bin] <= r0) { cb += hist[bin]; bin++; }
        int B0 = bin, cumB0 = cb;
        int bin1 = bin, cb1 = cb;
        while (cb1 + hist[bin1] <= r1) { cb1 += hist[bin1]; bin1++; }
        ctrl[0] = B0; ctrl[1] = bin1; ctrl[2] = cumB0;
    }
    __syncthreads();

    int B0 = ctrl[0], B1 = ctrl[1];
    for (int idx = t; idx < RR * RR; idx += 256) {
        int i = idx / RR, j = idx % RR;
        if (j < i) {
            float val = fabsf(Cb[idx]);
            int bin = (int)(val * (float)NBIN);
            bin = bin > (NBIN - 1) ? (NBIN - 1) : bin;
            if (bin >= B0 && bin <= B1) {
                int k = atomicAdd(&ctrl[3], 1);
                if (k < MAXCAND) cand[k] = val;
            }
        }
    }
    __syncthreads();

    if (t == 0) {
        int n = ctrl[3]; if (n > MAXCAND) n = MAXCAND;
        for (int i = 1; i < n; i++) {
            float key = cand[i]; int j = i - 1;
            while (j >= 0 && cand[j] > key) { cand[j + 1] = cand[j]; j--; }
            cand[j + 1] = key;
        }
        int r0 = 3647 - ctrl[2];
        int r1 = 3648 - ctrl[2];
        double v0 = (double)cand[r0], v1 = (double)cand[r1];
        thr[band] = v0 + 0.2 * (v1 - v0);   // pos = 0.8*(4560-1) = 3647.2
    }
}

// ---------- K4: graph props + node features + MLP; masks A in place, writes F ----------
__global__ __launch_bounds__(256) void graph_feat_kernel(
    const double* __restrict__ thrA,
    const double* __restrict__ rowstats, const int* __restrict__ community,
    const float* __restrict__ W1, const float* __restrict__ b1,
    const float* __restrict__ W2, const float* __restrict__ b2,
    float* __restrict__ A_out, float* __restrict__ F_out)
{
    __shared__ unsigned char Bm[RR][RR];
    __shared__ unsigned long long msk[RR][2];
    __shared__ int deg[RR];
    __shared__ double sred[8];
    __shared__ double feat[11];
    __shared__ double h[32];

    int band = blockIdx.x, t = threadIdx.x;
    double thr = thrA[band];
    float* Ab = A_out + (size_t)band * (RR * RR);

    for (int idx = t; idx < RR * RR; idx += 256) {
        float c = Ab[idx];
        bool keep = ((double)fabsf(c) >= thr);
        Bm[idx / RR][idx % RR] = (keep && c != 0.0f) ? 1 : 0;
        Ab[idx] = keep ? c : 0.0f;
    }
    __syncthreads();

    if (t < RR) {
        unsigned long long m0 = 0, m1 = 0; int d = 0;
        for (int j = 0; j < RR; j++) {
            if (Bm[t][j]) { d++; if (j < 64) m0 |= (1ull << j); else m1 |= (1ull << (j - 64)); }
        }
        msk[t][0] = m0; msk[t][1] = m1; deg[t] = d;
    }
    __syncthreads();

    double triord = 0, ein = 0, expin = 0;
    for (int idx = t; idx < RR * RR; idx += 256) {
        int i = idx / RR, j = idx % RR;
        if (Bm[i][j])
            triord += (double)(__popcll(msk[i][0] & msk[j][0]) +
                               __popcll(msk[i][1] & msk[j][1]));
        if (i != j && community[i] == community[j]) {
            ein += (double)Bm[i][j];
            expin += (double)deg[i] * (double)deg[j];
        }
    }
    double TRI   = blockReduceSum(triord, sred);
    double EIN   = blockReduceSum(ein, sred);
    double EXPIN = blockReduceSum(expin, sred);
    double dv = (t < RR) ? (double)deg[t] : 0.0;
    double DEGS = blockReduceSum(dv, sred);
    double POSS2 = blockReduceSum((t < RR) ? dv * (dv - 1.0) : 0.0, sred);

    const double* rs = rowstats + (size_t)band * RR * 6;
    double N0 = blockReduceSum((t < RR) ? rs[t * 6 + 0] : 0.0, sred);
    double N1 = blockReduceSum((t < RR) ? rs[t * 6 + 2] : 0.0, sred);
    double N2 = blockReduceSum((t < RR) ? rs[t * 6 + 3] : 0.0, sred);
    double N3 = blockReduceSum((t < RR) ? rs[t * 6 + 4] : 0.0, sred);
    double N4 = blockReduceSum((t < RR) ? rs[t * 6 + 5] : 0.0, sred);

    if (t == 0) {
        double ne = 0.5 * DEGS;
        feat[0] = N0 / (double)RR;
        feat[1] = N1 / (double)RR;
        feat[2] = N2 / (double)RR;
        feat[3] = N3 / (double)RR;
        feat[4] = N4 / (double)RR;
        feat[5] = ne;
        feat[6] = ne / (double)NTRIL;
        feat[7] = DEGS / (double)RR;
        double tri = TRI / 6.0, poss = POSS2 * 0.5;
        feat[8] = (poss > 0.0) ? tri / poss : 0.0;
        feat[9] = ((double)RR + DEGS) / ((double)RR * (double)(RR - 1));
        double m2 = DEGS;
        feat[10] = (m2 > 0.0) ? (EIN - EXPIN / m2) / m2 : 0.0;
    }
    __syncthreads();

    if (t < 32) {
        double a = (double)b1[t];
        for (int k = 0; k < 11; k++) a += (double)W1[t * 11 + k] * feat[k];
        h[t] = (a > 0.0) ? a : 0.0;
    }
    __syncthreads();
    if (t < 64) {
        double a = (double)b2[t];
        for (int j = 0; j < 32; j++) a += (double)W2[t * 32 + j] * h[j];
        F_out[(size_t)band * 64 + t] = (float)a;
    }
}

extern "C" void kernel_launch(void* const* d_in, const int* in_sizes, int n_in,
                              void* d_out, int out_size, void* d_ws, size_t ws_size,
                              hipStream_t stream) {
    const float* wc        = (const float*)d_in[0];
    // d_in[1] frequency_bands: unused by the reference math
    const int*   community = (const int*)d_in[2];
    const float* W1        = (const float*)d_in[3];
    const float* b1        = (const float*)d_in[4];
    const float* W2        = (const float*)d_in[5];
    const float* b2        = (const float*)d_in[6];

    float* A_out = (float*)d_out;          // Gram staged here, normalized, masked in place
    float* F_out = A_out + A_ELEMS;

    // workspace layout:
    //   tw        @ 0        (8192 B)
    //   rowstats  @ 8192     (15360*6*8 = 737280 B)
    //   thr       @ 745472   (160*8 = 1280 B)
    //   Gpart     @ 747520   (160*8*9216*4 = 47185920 B)  [if ws is big enough]
    char* ws = (char*)d_ws;
    float*  tw       = (float*)ws;
    double* rowstats = (double*)(ws + 8192);
    double* thr      = (double*)(ws + 745472);
    const size_t PART_OFF   = 747520;
    const size_t PART_BYTES = (size_t)NBANDS * KS * RR * RR * sizeof(float);
    float* Gpart = (float*)(ws + PART_OFF);
    bool use_part = (ws_size >= PART_OFF + PART_BYTES);

    hipLaunchKernelGGL(twiddle_kernel, dim3(4), dim3(256), 0, stream, tw);
    hipLaunchKernelGGL(rowstat_fft_kernel, dim3(NBANDS * RR / 2), dim3(256), 0, stream,
                       wc, tw, rowstats);
    if (use_part) {
        hipLaunchKernelGGL(HIP_KERNEL_NAME(gram_mfma_kernel<true>),
                           dim3(NBANDS * KS), dim3(384), 0, stream, wc, Gpart);
        hipLaunchKernelGGL(HIP_KERNEL_NAME(normalize_kernel<true>),
                           dim3((int)((NBANDS * RR * RR + 255) / 256)), dim3(256), 0, stream,
                           A_out, Gpart, rowstats);
    } else {
        int n4 = (int)(A_ELEMS / 4);       // 368640
        hipLaunchKernelGGL(zero_kernel, dim3((n4 + 255) / 256), dim3(256), 0, stream,
                           (float4*)A_out, n4);
        hipLaunchKernelGGL(HIP_KERNEL_NAME(gram_mfma_kernel<false>),
                           dim3(NBANDS * KS), dim3(384), 0, stream, wc, A_out);
        hipLaunchKernelGGL(HIP_KERNEL_NAME(normalize_kernel<false>),
                           dim3((int)((NBANDS * RR * RR + 255) / 256)), dim3(256), 0, stream,
                           A_out, A_out, rowstats);
    }
    hipLaunchKernelGGL(quantile_kernel, dim3(NBANDS), dim3(256), 0, stream, A_out, thr);
    hipLaunchKernelGGL(graph_feat_kernel, dim3(NBANDS), dim3(256), 0, stream,
                       thr, rowstats, community, W1, b1, W2, b2, A_out, F_out);
}

// Round 2
// 309.666 us; speedup vs baseline: 1.1650x; 1.0431x over previous
//
#include <hip/hip_runtime.h>
#include <hip/hip_bf16.h>
#include <math.h>
#include <float.h>

#ifndef M_PI
#define M_PI 3.14159265358979323846
#endif

// Problem constants
#define NBANDS 160      // B*NB = 32*5
#define RR 96           // rows per band
#define TT 2048         // time samples
#define NTRIL 4560      // 96*95/2
#define A_ELEMS ((size_t)NBANDS * RR * RR)
#define NBIN 16384
#define MAXCAND 512

#define KS 8
#define CHUNK 256
#define BKS 64
#define GPITCH 72

// XOR bank swizzle for the FFT kernel
#define PHI(L) ((L) ^ (((L) >> 5) & 31))

typedef float  f32x4  __attribute__((ext_vector_type(4)));
typedef __bf16 bf16x8 __attribute__((ext_vector_type(8)));
typedef __bf16 bf16x4 __attribute__((ext_vector_type(4)));

// ---------- block reductions (256 threads = 4 waves) ----------
__device__ inline void blockReduceSum4(double v0, double v1, double v2, double v3,
                                       double* sred, double out[4]) {
    for (int off = 32; off > 0; off >>= 1) {
        v0 += __shfl_down(v0, off, 64);
        v1 += __shfl_down(v1, off, 64);
        v2 += __shfl_down(v2, off, 64);
        v3 += __shfl_down(v3, off, 64);
    }
    int lane = threadIdx.x & 63, wid = threadIdx.x >> 6;
    if (lane == 0) {
        sred[wid * 4 + 0] = v0; sred[wid * 4 + 1] = v1;
        sred[wid * 4 + 2] = v2; sred[wid * 4 + 3] = v3;
    }
    __syncthreads();
    if (threadIdx.x < 4) {
        double r = sred[threadIdx.x] + sred[4 + threadIdx.x]
                 + sred[8 + threadIdx.x] + sred[12 + threadIdx.x];
        sred[16 + threadIdx.x] = r;
    }
    __syncthreads();
    out[0] = sred[16]; out[1] = sred[17]; out[2] = sred[18]; out[3] = sred[19];
    __syncthreads();
}

__device__ inline void blockReduceSum2(double v0, double v1,
                                       double* sred, double out[2]) {
    for (int off = 32; off > 0; off >>= 1) {
        v0 += __shfl_down(v0, off, 64);
        v1 += __shfl_down(v1, off, 64);
    }
    int lane = threadIdx.x & 63, wid = threadIdx.x >> 6;
    if (lane == 0) { sred[wid * 2 + 0] = v0; sred[wid * 2 + 1] = v1; }
    __syncthreads();
    if (threadIdx.x < 2) {
        double r = sred[threadIdx.x] + sred[2 + threadIdx.x]
                 + sred[4 + threadIdx.x] + sred[6 + threadIdx.x];
        sred[8 + threadIdx.x] = r;
    }
    __syncthreads();
    out[0] = sred[8]; out[1] = sred[9];
    __syncthreads();
}

__device__ inline void blockReduceMax4(double v0, double v1, double v2, double v3,
                                       double* sred, double out[4]) {
    for (int off = 32; off > 0; off >>= 1) {
        v0 = fmax(v0, __shfl_down(v0, off, 64));
        v1 = fmax(v1, __shfl_down(v1, off, 64));
        v2 = fmax(v2, __shfl_down(v2, off, 64));
        v3 = fmax(v3, __shfl_down(v3, off, 64));
    }
    int lane = threadIdx.x & 63, wid = threadIdx.x >> 6;
    if (lane == 0) {
        sred[wid * 4 + 0] = v0; sred[wid * 4 + 1] = v1;
        sred[wid * 4 + 2] = v2; sred[wid * 4 + 3] = v3;
    }
    __syncthreads();
    if (threadIdx.x < 4) {
        double r = fmax(fmax(sred[threadIdx.x], sred[4 + threadIdx.x]),
                        fmax(sred[8 + threadIdx.x], sred[12 + threadIdx.x]));
        sred[16 + threadIdx.x] = r;
    }
    __syncthreads();
    out[0] = sred[16]; out[1] = sred[17]; out[2] = sred[18]; out[3] = sred[19];
    __syncthreads();
}

// ---------- K0: twiddle table  tw[k] = exp(-2*pi*i*k/2048), k<1024 (fp32) ----------
__global__ void twiddle_kernel(float* tw) {
    int k = blockIdx.x * blockDim.x + threadIdx.x;
    if (k < 1024) {
        double ang = -2.0 * M_PI * (double)k / 2048.0;
        tw[2 * k]     = (float)cos(ang);
        tw[2 * k + 1] = (float)sin(ang);
    }
}

// dual butterfly: same twiddle applied to two independent FFTs (ILP x2)
#define BFLYD(r1, r2, WR, WI) do { \
    float _wr = (WR), _wi = (WI); \
    float _t1r = _wr * yr1[r2] - _wi * yi1[r2]; \
    float _t1i = _wr * yi1[r2] + _wi * yr1[r2]; \
    yr1[r2] = yr1[r1] - _t1r; yi1[r2] = yi1[r1] - _t1i; \
    yr1[r1] += _t1r; yi1[r1] += _t1i; \
    float _t2r = _wr * yr2[r2] - _wi * yi2[r2]; \
    float _t2i = _wr * yi2[r2] + _wi * yr2[r2]; \
    yr2[r2] = yr2[r1] - _t2r; yi2[r2] = yi2[r1] - _t2i; \
    yr2[r1] += _t2r; yi2[r1] += _t2i; } while (0)

// ---------- K1: per-row stats + two interleaved fp32 radix-8 FFTs ----------
// 4 rows per block = 2 complex FFTs (rows 2k/2k+1 packed re/im). Doubling the
// in-thread ILP fills the dependent-butterfly latency the 2-row version left
// (VALUBusy 64%); barrier count per row halves; twiddle loads shared + float2.
__global__ __launch_bounds__(256) void rowstat_fft_kernel(
    const float* __restrict__ wc, const float* __restrict__ tw,
    double* __restrict__ rowstats)
{
    __shared__ float re1[TT];
    __shared__ float im1[TT];
    __shared__ float re2[TT];
    __shared__ float im2[TT];
    __shared__ double sred[24];
    __shared__ double statout[12];
    __shared__ float bcast[8];

    int t = threadIdx.x;
    int g0 = blockIdx.x * 4;

    int band = g0 / RR, r0 = g0 % RR;      // 96 % 4 == 0: all 4 rows same band
    int b = band / 5, nb = band % 5;
    size_t base0 = ((size_t)(b * RR + r0) * 5 + nb) * TT;
    const size_t RSTR = (size_t)5 * TT;
    const float2* twv = (const float2*)tw;

    float s0 = 0.f, s1 = 0.f, s2 = 0.f, s3 = 0.f;
    float q0 = 0.f, q1 = 0.f, q2 = 0.f, q3 = 0.f;
    float m0 = 0.f, m1 = 0.f, m2 = 0.f, m3 = 0.f;
#pragma unroll
    for (int c = 0; c < 8; c++) {
        int i = t + c * 256;
        float a0 = wc[base0 + i];
        float a1 = wc[base0 + RSTR + i];
        float a2 = wc[base0 + 2 * RSTR + i];
        float a3 = wc[base0 + 3 * RSTR + i];
        int P = PHI(i);
        re1[P] = a0; im1[P] = a1; re2[P] = a2; im2[P] = a3;
        s0 += a0; s1 += a1; s2 += a2; s3 += a3;
        q0 = fmaf(a0, a0, q0); q1 = fmaf(a1, a1, q1);
        q2 = fmaf(a2, a2, q2); q3 = fmaf(a3, a3, q3);
        m0 = fmaxf(m0, fabsf(a0)); m1 = fmaxf(m1, fabsf(a1));
        m2 = fmaxf(m2, fabsf(a2)); m3 = fmaxf(m3, fabsf(a3));
    }
    __syncthreads();

    {
        double S[4], Q[4], M[4];
        blockReduceSum4((double)s0, (double)s1, (double)s2, (double)s3, sred, S);
        blockReduceSum4((double)q0, (double)q1, (double)q2, (double)q3, sred, Q);
        blockReduceMax4((double)m0, (double)m1, (double)m2, (double)m3, sred, M);
        if (t == 0) {
            statout[0] = S[0]; statout[1] = S[1]; statout[2] = S[2]; statout[3] = S[3];
            statout[4] = Q[0]; statout[5] = Q[1]; statout[6] = Q[2]; statout[7] = Q[3];
            statout[8] = M[0]; statout[9] = M[1]; statout[10] = M[2]; statout[11] = M[3];
        }
    }
    // park stats in LDS so S/Q/M don't occupy VGPRs through the FFT body

    float yr1[8], yi1[8], yr2[8], yi2[8];

#pragma unroll
    for (int j = 0; j < 8; j++) {
        int p = 8 * t + j;
        int L = (int)(__brev((unsigned)p) >> 21);
        int P = PHI(L);
        yr1[j] = re1[P]; yi1[j] = im1[P];
        yr2[j] = re2[P]; yi2[j] = im2[P];
    }

    const float RC = 0.70710678f;
    BFLYD(0, 1, 1.0f, 0.0f); BFLYD(2, 3, 1.0f, 0.0f);
    BFLYD(4, 5, 1.0f, 0.0f); BFLYD(6, 7, 1.0f, 0.0f);
    BFLYD(0, 2, 1.0f, 0.0f); BFLYD(1, 3, 0.0f, -1.0f);
    BFLYD(4, 6, 1.0f, 0.0f); BFLYD(5, 7, 0.0f, -1.0f);
    BFLYD(0, 4, 1.0f, 0.0f); BFLYD(1, 5, RC, -RC);
    BFLYD(2, 6, 0.0f, -1.0f); BFLYD(3, 7, -RC, -RC);

    __syncthreads();
#pragma unroll
    for (int j = 0; j < 8; j++) {
        int P = PHI(8 * t + j);
        re1[P] = yr1[j]; im1[P] = yi1[j];
        re2[P] = yr2[j]; im2[P] = yi2[j];
    }
    __syncthreads();
    int oo = t & 7;
    int bb64 = 4 * ((t >> 3) & 7) + (t >> 6);
#pragma unroll
    for (int k = 0; k < 8; k++) {
        int P = PHI(64 * bb64 + 8 * k + oo);
        yr1[k] = re1[P]; yi1[k] = im1[P];
        yr2[k] = re2[P]; yi2[k] = im2[P];
    }

    {
        float2 w0 = twv[oo << 7];
        BFLYD(0, 1, w0.x, w0.y); BFLYD(2, 3, w0.x, w0.y);
        BFLYD(4, 5, w0.x, w0.y); BFLYD(6, 7, w0.x, w0.y);
        float2 wa = twv[oo << 6];
        float2 wb = twv[(oo + 8) << 6];
        BFLYD(0, 2, wa.x, wa.y); BFLYD(1, 3, wb.x, wb.y);
        BFLYD(4, 6, wa.x, wa.y); BFLYD(5, 7, wb.x, wb.y);
        float2 wc0 = twv[oo << 5], wc1 = twv[(oo + 8) << 5];
        float2 wc2 = twv[(oo + 16) << 5], wc3 = twv[(oo + 24) << 5];
        BFLYD(0, 4, wc0.x, wc0.y);
        BFLYD(1, 5, wc1.x, wc1.y);
        BFLYD(2, 6, wc2.x, wc2.y);
        BFLYD(3, 7, wc3.x, wc3.y);
    }

    __syncthreads();
#pragma unroll
    for (int k = 0; k < 8; k++) {
        int P = PHI(64 * bb64 + 8 * k + oo);
        re1[P] = yr1[k]; im1[P] = yi1[k];
        re2[P] = yr2[k]; im2[P] = yi2[k];
    }
    __syncthreads();
    int O3 = t & 63, Wq = t >> 6;
#pragma unroll
    for (int s = 0; s < 2; s++) {
        int B3 = Wq + 4 * s;
#pragma unroll
        for (int k = 0; k < 4; k++) {
            int P = PHI(256 * B3 + 64 * k + O3);
            yr1[4 * s + k] = re1[P]; yi1[4 * s + k] = im1[P];
            yr2[4 * s + k] = re2[P]; yi2[4 * s + k] = im2[P];
        }
    }

    {
        float2 w0 = twv[O3 << 4];
        float2 wa = twv[O3 << 3];
        float2 wb = twv[(O3 + 64) << 3];
        BFLYD(0, 1, w0.x, w0.y); BFLYD(2, 3, w0.x, w0.y);
        BFLYD(4, 5, w0.x, w0.y); BFLYD(6, 7, w0.x, w0.y);
        BFLYD(0, 2, wa.x, wa.y); BFLYD(1, 3, wb.x, wb.y);
        BFLYD(4, 6, wa.x, wa.y); BFLYD(5, 7, wb.x, wb.y);
    }

    __syncthreads();
#pragma unroll
    for (int s = 0; s < 2; s++) {
        int B3 = Wq + 4 * s;
#pragma unroll
        for (int k = 0; k < 4; k++) {
            int P = PHI(256 * B3 + 64 * k + O3);
            re1[P] = yr1[4 * s + k]; im1[P] = yi1[4 * s + k];
            re2[P] = yr2[4 * s + k]; im2[P] = yi2[4 * s + k];
        }
    }
    __syncthreads();
#pragma unroll
    for (int k = 0; k < 8; k++) {
        int P = PHI(256 * k + t);
        yr1[k] = re1[P]; yi1[k] = im1[P];
        yr2[k] = re2[P]; yi2[k] = im2[P];
    }

    {
        float2 w0 = twv[t << 2];
        float2 wa = twv[t << 1];
        float2 wb = twv[(t + 256) << 1];
        BFLYD(0, 1, w0.x, w0.y); BFLYD(2, 3, w0.x, w0.y);
        BFLYD(4, 5, w0.x, w0.y); BFLYD(6, 7, w0.x, w0.y);
        BFLYD(0, 2, wa.x, wa.y); BFLYD(1, 3, wb.x, wb.y);
        BFLYD(4, 6, wa.x, wa.y); BFLYD(5, 7, wb.x, wb.y);
        float2 wf0 = twv[t], wf1 = twv[t + 256];
        float2 wf2 = twv[t + 512], wf3 = twv[t + 768];
        BFLYD(0, 4, wf0.x, wf0.y);
        BFLYD(1, 5, wf1.x, wf1.y);
        BFLYD(2, 6, wf2.x, wf2.y);
        BFLYD(3, 7, wf3.x, wf3.y);
    }

    __syncthreads();
#pragma unroll
    for (int k = 0; k < 8; k++) {
        int P = PHI(256 * k + t);
        re1[P] = yr1[k]; im1[P] = yi1[k];
        re2[P] = yr2[k]; im2[P] = yi2[k];
    }
    __syncthreads();

    float psa1[8], psb1[8], psa2[8], psb2[8];
#pragma unroll
    for (int k = 0; k < 8; k++) {
        int q = (2048 - t - 256 * k) & 2047;
        int P = PHI(q);
        float prr = re1[P], pii = im1[P];
        float sr = yr1[k] + prr, di = yi1[k] - pii;
        float si = yi1[k] + pii, dr = yr1[k] - prr;
        psa1[k] = 0.25f * (sr * sr + di * di);
        psb1[k] = 0.25f * (si * si + dr * dr);
        float prr2 = re2[P], pii2 = im2[P];
        float sr2 = yr2[k] + prr2, di2 = yi2[k] - pii2;
        float si2 = yi2[k] + pii2, dr2 = yr2[k] - prr2;
        psa2[k] = 0.25f * (sr2 * sr2 + di2 * di2);
        psb2[k] = 0.25f * (si2 * si2 + dr2 * dr2);
    }

    float la = 0.f, lb = 0.f, lc = 0.f, ld = 0.f;
#pragma unroll
    for (int k = 0; k < 8; k++) {
        la += psa1[k]; lb += psb1[k]; lc += psa2[k]; ld += psb2[k];
    }
    double SS[4];
    blockReduceSum4((double)la, (double)lb, (double)lc, (double)ld, sred, SS);
    if (t == 0) {
        bcast[0] = psa1[0]; bcast[1] = psa1[4];
        bcast[2] = psb1[0]; bcast[3] = psb1[4];
        bcast[4] = psa2[0]; bcast[5] = psa2[4];
        bcast[6] = psb2[0]; bcast[7] = psb2[4];
    }
    __syncthreads();
    double Sa = 0.5 * (SS[0] + (double)bcast[0] - (double)bcast[1]);
    double Sb = 0.5 * (SS[1] + (double)bcast[2] - (double)bcast[3]);
    double Sc = 0.5 * (SS[2] + (double)bcast[4] - (double)bcast[5]);
    double Sd = 0.5 * (SS[3] + (double)bcast[6] - (double)bcast[7]);
    if (Sa == 0.0) Sa = 1.0;
    if (Sb == 0.0) Sb = 1.0;
    if (Sc == 0.0) Sc = 1.0;
    if (Sd == 0.0) Sd = 1.0;
    float invSa = (float)(1.0 / Sa), invSb = (float)(1.0 / Sb);
    float invSc = (float)(1.0 / Sc), invSd = (float)(1.0 / Sd);

    float ea = 0.f, eb = 0.f, ec = 0.f, ed = 0.f;
#pragma unroll
    for (int k = 0; k < 8; k++) {
        float pa = psa1[k] * invSa;
        float pb = psb1[k] * invSb;
        float pc = psa2[k] * invSc;
        float pd = psb2[k] * invSd;
        ea += pa * __logf(pa + 1e-10f);
        eb += pb * __logf(pb + 1e-10f);
        ec += pc * __logf(pc + 1e-10f);
        ed += pd * __logf(pd + 1e-10f);
    }
    double EE[4];
    blockReduceSum4((double)ea, (double)eb, (double)ec, (double)ed, sred, EE);

    if (t == 0) {
        float pa0 = psa1[0] * invSa, pa4 = psa1[4] * invSa;
        float pb0 = psb1[0] * invSb, pb4 = psb1[4] * invSb;
        float pc0 = psa2[0] * invSc, pc4 = psa2[4] * invSc;
        float pd0 = psb2[0] * invSd, pd4 = psb2[4] * invSd;
        double TA = 0.5 * (EE[0] + (double)(pa0 * __logf(pa0 + 1e-10f))
                                 - (double)(pa4 * __logf(pa4 + 1e-10f)));
        double TB = 0.5 * (EE[1] + (double)(pb0 * __logf(pb0 + 1e-10f))
                                 - (double)(pb4 * __logf(pb4 + 1e-10f)));
        double TC = 0.5 * (EE[2] + (double)(pc0 * __logf(pc0 + 1e-10f))
                                 - (double)(pc4 * __logf(pc4 + 1e-10f)));
        double TD = 0.5 * (EE[3] + (double)(pd0 * __logf(pd0 + 1e-10f))
                                 - (double)(pd4 * __logf(pd4 + 1e-10f)));
        double TAs[4] = {TA, TB, TC, TD};
#pragma unroll
        for (int rix = 0; rix < 4; rix++) {
            double SUM = statout[rix], SQ = statout[4 + rix], MX = statout[8 + rix];
            double mean = SUM / (double)TT;
            double nsq = SQ - (double)TT * mean * mean; if (nsq < 0) nsq = 0;
            double nrm = sqrt(nsq);
            double* w = rowstats + (size_t)(g0 + rix) * 6;
            w[0] = mean; w[1] = (nrm == 0.0 ? 1.0 : nrm); w[2] = sqrt(nsq / 2047.0);
            w[3] = SQ;   w[4] = MX;                       w[5] = -TAs[rix];
        }
    }
}

// ---------- K2a: zero the Gram staging region (fallback path only) ----------
__global__ void zero_kernel(float4* __restrict__ p, int n4) {
    int i = blockIdx.x * blockDim.x + threadIdx.x;
    if (i < n4) p[i] = make_float4(0.f, 0.f, 0.f, 0.f);
}

// ---------- K2b: MFMA Gram (hi/lo bf16 split, fp32 MFMA accum) ----------
template <bool USE_PART>
__global__ __launch_bounds__(384) void gram_mfma_kernel(
    const float* __restrict__ wc, float* __restrict__ G)
{
    __shared__ __attribute__((aligned(16))) __bf16 sh_hi[RR][GPITCH];
    __shared__ __attribute__((aligned(16))) __bf16 sh_lo[RR][GPITCH];

    int bid = blockIdx.x;
    int band = bid / KS, chunk = bid % KS;
    int b = band / 5, nb = band % 5;
    size_t bandbase = ((size_t)b * RR * 5 + nb) * TT + (size_t)chunk * CHUNK;

    int t = threadIdx.x;
    int wave = t >> 6, lane = t & 63;
    int m16 = lane & 15, quad = lane >> 4;
    int arow = wave * 16 + m16;

    f32x4 acc[6];
#pragma unroll
    for (int ct = 0; ct < 6; ct++) acc[ct] = (f32x4){0.f, 0.f, 0.f, 0.f};

    for (int stage = 0; stage < CHUNK / BKS; stage++) {
        int k0 = stage * BKS;
#pragma unroll
        for (int i = 0; i < 4; i++) {
            int gid = t + i * 384;          // 0..1535
            int row = gid >> 4, c4 = gid & 15;
            float4 v = *(const float4*)(wc + bandbase + (size_t)row * (5 * TT) + k0 + c4 * 4);
            __bf16 h0 = (__bf16)v.x, h1 = (__bf16)v.y, h2 = (__bf16)v.z, h3 = (__bf16)v.w;
            __bf16 l0 = (__bf16)(v.x - (float)h0);
            __bf16 l1 = (__bf16)(v.y - (float)h1);
            __bf16 l2 = (__bf16)(v.z - (float)h2);
            __bf16 l3 = (__bf16)(v.w - (float)h3);
            *(bf16x4*)&sh_hi[row][c4 * 4] = (bf16x4){h0, h1, h2, h3};
            *(bf16x4*)&sh_lo[row][c4 * 4] = (bf16x4){l0, l1, l2, l3};
        }
        __syncthreads();
#pragma unroll
        for (int ks = 0; ks < BKS / 32; ks++) {
            int ko = ks * 32 + quad * 8;
            bf16x8 ah = *(const bf16x8*)&sh_hi[arow][ko];
            bf16x8 al = *(const bf16x8*)&sh_lo[arow][ko];
#pragma unroll
            for (int ct = 0; ct < 6; ct++) {
                int brow = ct * 16 + m16;
                bf16x8 bh = *(const bf16x8*)&sh_hi[brow][ko];
                bf16x8 bl = *(const bf16x8*)&sh_lo[brow][ko];
                acc[ct] = __builtin_amdgcn_mfma_f32_16x16x32_bf16(ah, bh, acc[ct], 0, 0, 0);
                acc[ct] = __builtin_amdgcn_mfma_f32_16x16x32_bf16(ah, bl, acc[ct], 0, 0, 0);
                acc[ct] = __builtin_amdgcn_mfma_f32_16x16x32_bf16(al, bh, acc[ct], 0, 0, 0);
            }
        }
        __syncthreads();
    }

    if (USE_PART) {
        float* Gp = G + (size_t)bid * (RR * RR);   // per-chunk partial tile
#pragma unroll
        for (int ct = 0; ct < 6; ct++) {
#pragma unroll
            for (int r = 0; r < 4; r++) {
                int grow = wave * 16 + quad * 4 + r;
                int gcol = ct * 16 + m16;
                Gp[grow * RR + gcol] = acc[ct][r];
            }
        }
    } else {
        float* Gb = G + (size_t)band * (RR * RR);
#pragma unroll
        for (int ct = 0; ct < 6; ct++) {
#pragma unroll
            for (int r = 0; r < 4; r++) {
                int grow = wave * 16 + quad * 4 + r;
                int gcol = ct * 16 + m16;
                atomicAdd(&Gb[grow * RR + gcol], acc[ct][r]);
            }
        }
    }
}

// ---------- K3: fused per-band finalize ----------
// normalize (+partial sum) -> C in LDS -> histogram quantile -> masked A write
// -> ballot bitmask graph props -> MLP -> F. One kernel instead of three; C
// never round-trips through global except the single final masked write.
template <bool USE_PART>
__global__ __launch_bounds__(256) void band_finalize_kernel(
    const float* __restrict__ Gsrc, const double* __restrict__ rowstats,
    const int* __restrict__ community,
    const float* __restrict__ W1, const float* __restrict__ b1,
    const float* __restrict__ W2, const float* __restrict__ b2,
    float* __restrict__ A_out, float* __restrict__ F_out)
{
    __shared__ float Cs[RR][RR];               // 36 KB
    __shared__ int hist[NBIN];                 // 64 KB
    __shared__ int chunkv[256];
    __shared__ float cand[MAXCAND];
    __shared__ int ctrl[4];
    __shared__ double mean_s[RR], nrm_s[RR];
    __shared__ int comm_s[RR];
    __shared__ unsigned long long msk[RR][2];
    __shared__ int deg[RR];
    __shared__ double sred[24];
    __shared__ double feat[11];
    __shared__ double hmlp[32];
    __shared__ double thr_s;

    int band = blockIdx.x, t = threadIdx.x;
    const double* rsb = rowstats + (size_t)band * RR * 6;
    if (t < RR) {
        mean_s[t] = rsb[t * 6 + 0];
        nrm_s[t]  = rsb[t * 6 + 1];
        comm_s[t] = community[t];
    }
    for (int i = t; i < NBIN; i += 256) hist[i] = 0;
    if (t == 0) ctrl[3] = 0;
    __syncthreads();

    // normalize (+ 8-way partial sum) into LDS, histogram tril on the fly
    for (int idx = t; idx < RR * RR; idx += 256) {
        int i = idx / RR, j = idx % RR;
        float g;
        if (USE_PART) {
            const float* p = Gsrc + (size_t)band * KS * (RR * RR) + idx;
            float acc = 0.f;
#pragma unroll
            for (int c = 0; c < KS; c++) acc += p[(size_t)c * (RR * RR)];
            g = acc;
        } else {
            g = Gsrc[(size_t)band * (RR * RR) + idx];
        }
        double cd = ((double)g - (double)TT * mean_s[i] * mean_s[j]) / (nrm_s[i] * nrm_s[j]);
        if (i == j) cd = 0.0;
        float cf = (float)cd;
        Cs[i][j] = cf;
        if (j < i) {
            float val = fabsf(cf);
            int bin = (int)(val * (float)NBIN);
            bin = bin > (NBIN - 1) ? (NBIN - 1) : bin;
            atomicAdd(&hist[bin], 1);
        }
    }
    __syncthreads();

    int cs = 0;
    for (int i = 0; i < 64; i++) cs += hist[t * 64 + i];
    chunkv[t] = cs;
    __syncthreads();

    if (t == 0) {
        int r0 = 3647, r1 = 3648;
        int cum = 0, c0 = 0;
        while (c0 < 256 && cum + chunkv[c0] <= r0) { cum += chunkv[c0]; c0++; }
        int bin = c0 * 64, cb = cum;
        while (cb + hist[bin] <= r0) { cb += hist[bin]; bin++; }
        int B0 = bin, cumB0 = cb;
        int bin1 = bin, cb1 = cb;
        while (cb1 + hist[bin1] <= r1) { cb1 += hist[bin1]; bin1++; }
        ctrl[0] = B0; ctrl[1] = bin1; ctrl[2] = cumB0;
    }
    __syncthreads();

    int B0 = ctrl[0], B1 = ctrl[1];
    for (int idx = t; idx < RR * RR; idx += 256) {
        int i = idx / RR, j = idx % RR;
        if (j < i) {
            float val = fabsf(Cs[i][j]);
            int bin = (int)(val * (float)NBIN);
            bin = bin > (NBIN - 1) ? (NBIN - 1) : bin;
            if (bin >= B0 && bin <= B1) {
                int k = atomicAdd(&ctrl[3], 1);
                if (k < MAXCAND) cand[k] = val;
            }
        }
    }
    __syncthreads();

    if (t == 0) {
        int n = ctrl[3]; if (n > MAXCAND) n = MAXCAND;
        for (int i = 1; i < n; i++) {
            float key = cand[i]; int j = i - 1;
            while (j >= 0 && cand[j] > key) { cand[j + 1] = cand[j]; j--; }
            cand[j + 1] = key;
        }
        int r0 = 3647 - ctrl[2];
        int r1 = 3648 - ctrl[2];
        double v0 = (double)cand[r0], v1 = (double)cand[r1];
        thr_s = v0 + 0.2 * (v1 - v0);       // pos = 0.8*(4560-1) = 3647.2
    }
    __syncthreads();
    double thr = thr_s;

    // masked A write (single pass, coalesced)
    float* Ab = A_out + (size_t)band * (RR * RR);
    for (int idx = t; idx < RR * RR; idx += 256) {
        float cf = Cs[idx / RR][idx % RR];
        bool keep = ((double)fabsf(cf) >= thr);
        Ab[idx] = keep ? cf : 0.f;
    }

    // adjacency bitmasks via ballot: wave w handles rows w, w+4, ...
    int lane = t & 63, wid = t >> 6;
    for (int i = wid; i < RR; i += 4) {
        float vlo = Cs[i][lane];
        bool klo = ((double)fabsf(vlo) >= thr) && (vlo != 0.f);
        unsigned long long blo = __ballot(klo);
        float vhi = Cs[i][64 + (lane & 31)];
        bool khi = (lane < 32) && ((double)fabsf(vhi) >= thr) && (vhi != 0.f);
        unsigned long long bhi = __ballot(khi) & 0xffffffffull;
        if (lane == 0) {
            msk[i][0] = blo; msk[i][1] = bhi;
            deg[i] = __popcll(blo) + __popcll(bhi);
        }
    }
    __syncthreads();

    double triord = 0, ein = 0, expin = 0;
    for (int idx = t; idx < RR * RR; idx += 256) {
        int i = idx / RR, j = idx % RR;
        unsigned long long mi0 = msk[i][0], mi1 = msk[i][1];
        bool bij = (((j < 64) ? (mi0 >> j) : (mi1 >> (j - 64))) & 1ull) != 0;
        if (bij)
            triord += (double)(__popcll(mi0 & msk[j][0]) +
                               __popcll(mi1 & msk[j][1]));
        if (i != j && comm_s[i] == comm_s[j]) {
            ein += bij ? 1.0 : 0.0;
            expin += (double)deg[i] * (double)deg[j];
        }
    }
    double dv = (t < RR) ? (double)deg[t] : 0.0;
    double R1[4], R2[4], R3[2];
    blockReduceSum4(triord, ein, expin, dv, sred, R1);
    blockReduceSum4((t < RR) ? dv * (dv - 1.0) : 0.0,
                    (t < RR) ? rsb[t * 6 + 0] : 0.0,
                    (t < RR) ? rsb[t * 6 + 2] : 0.0,
                    (t < RR) ? rsb[t * 6 + 3] : 0.0, sred, R2);
    blockReduceSum2((t < RR) ? rsb[t * 6 + 4] : 0.0,
                    (t < RR) ? rsb[t * 6 + 5] : 0.0, sred, R3);
    double TRI = R1[0], EIN = R1[1], EXPIN = R1[2], DEGS = R1[3];
    double POSS2 = R2[0], N0 = R2[1], N1 = R2[2], N2 = R2[3];
    double N3 = R3[0], N4 = R3[1];

    if (t == 0) {
        double ne = 0.5 * DEGS;
        feat[0] = N0 / (double)RR;
        feat[1] = N1 / (double)RR;
        feat[2] = N2 / (double)RR;
        feat[3] = N3 / (double)RR;
        feat[4] = N4 / (double)RR;
        feat[5] = ne;
        feat[6] = ne / (double)NTRIL;
        feat[7] = DEGS / (double)RR;
        double tri = TRI / 6.0, poss = POSS2 * 0.5;
        feat[8] = (poss > 0.0) ? tri / poss : 0.0;
        feat[9] = ((double)RR + DEGS) / ((double)RR * (double)(RR - 1));
        double m2 = DEGS;
        feat[10] = (m2 > 0.0) ? (EIN - EXPIN / m2) / m2 : 0.0;
    }
    __syncthreads();

    if (t < 32) {
        double a = (double)b1[t];
        for (int k = 0; k < 11; k++) a += (double)W1[t * 11 + k] * feat[k];
        hmlp[t] = (a > 0.0) ? a : 0.0;
    }
    __syncthreads();
    if (t < 64) {
        double a = (double)b2[t];
        for (int j = 0; j < 32; j++) a += (double)W2[t * 32 + j] * hmlp[j];
        F_out[(size_t)band * 64 + t] = (float)a;
    }
}

extern "C" void kernel_launch(void* const* d_in, const int* in_sizes, int n_in,
                              void* d_out, int out_size, void* d_ws, size_t ws_size,
                              hipStream_t stream) {
    const float* wc        = (const float*)d_in[0];
    // d_in[1] frequency_bands: unused by the reference math
    const int*   community = (const int*)d_in[2];
    const float* W1        = (const float*)d_in[3];
    const float* b1        = (const float*)d_in[4];
    const float* W2        = (const float*)d_in[5];
    const float* b2        = (const float*)d_in[6];

    float* A_out = (float*)d_out;
    float* F_out = A_out + A_ELEMS;

    // workspace layout:
    //   tw        @ 0        (8192 B)
    //   rowstats  @ 8192     (15360*6*8 = 737280 B)
    //   Gpart     @ 747520   (160*8*9216*4 = 47185920 B)  [if ws is big enough]
    char* ws = (char*)d_ws;
    float*  tw       = (float*)ws;
    double* rowstats = (double*)(ws + 8192);
    const size_t PART_OFF   = 747520;
    const size_t PART_BYTES = (size_t)NBANDS * KS * RR * RR * sizeof(float);
    float* Gpart = (float*)(ws + PART_OFF);
    bool use_part = (ws_size >= PART_OFF + PART_BYTES);

    hipLaunchKernelGGL(twiddle_kernel, dim3(4), dim3(256), 0, stream, tw);
    hipLaunchKernelGGL(rowstat_fft_kernel, dim3(NBANDS * RR / 4), dim3(256), 0, stream,
                       wc, tw, rowstats);
    if (use_part) {
        hipLaunchKernelGGL(HIP_KERNEL_NAME(gram_mfma_kernel<true>),
                           dim3(NBANDS * KS), dim3(384), 0, stream, wc, Gpart);
        hipLaunchKernelGGL(HIP_KERNEL_NAME(band_finalize_kernel<true>),
                           dim3(NBANDS), dim3(256), 0, stream,
                           Gpart, rowstats, community, W1, b1, W2, b2, A_out, F_out);
    } else {
        int n4 = (int)(A_ELEMS / 4);       // 368640
        hipLaunchKernelGGL(zero_kernel, dim3((n4 + 255) / 256), dim3(256), 0, stream,
                           (float4*)A_out, n4);
        hipLaunchKernelGGL(HIP_KERNEL_NAME(gram_mfma_kernel<false>),
                           dim3(NBANDS * KS), dim3(384), 0, stream, wc, A_out);
        hipLaunchKernelGGL(HIP_KERNEL_NAME(band_finalize_kernel<false>),
                           dim3(NBANDS), dim3(256), 0, stream,
                           A_out, rowstats, community, W1, b1, W2, b2, A_out, F_out);
    }
}